// Round 9
// baseline (145.640 us; speedup 1.0000x reference)
//
#include <hip/hip_runtime.h>
#include <math.h>

#define OUT 7
#define NVOX 343          // 7*7*7
#define VSLOT 56          // lane-groups per block (49 real voxels + 7 null)
#define VREAL 49          // voxels per block = one ox-plane (7*7)
#define NCHP 7            // chunks per box (= OUT x-planes)
#define TPB 448           // 56 slots * 8 lanes = 7 waves

typedef unsigned short u16;
typedef unsigned int u32;

__device__ __forceinline__ u16 f32_to_bf16(float f) {
    u32 u = __float_as_uint(f);
    u32 r = (u + 0x7fffu + ((u >> 16) & 1u)) >> 16;   // RNE
    return (u16)r;
}
__device__ __forceinline__ float bf16_to_f32(u16 h) {
    return __uint_as_float(((u32)h) << 16);
}

__device__ __forceinline__ void axis_samp(float c, float fdim, int dim,
                                          int& lo, float& w0, float& w1) {
    float valid = (c > -1.0f && c < fdim) ? 1.0f : 0.0f;
    float cc = fminf(fmaxf(c, 0.0f), fdim - 1.0f);
    lo = (int)floorf(cc);
    float fr = cc - (float)lo;
    w0 = (1.0f - fr) * valid;
    w1 = fr * valid;     // == 0 whenever hi would clamp
}

__device__ __forceinline__ void box_setup(const float* bp,
                                          int d0, int d1, int d2_, int d3,
                                          int& l, int& dim, float& fdim,
                                          float& st0, float& st1, float& st2,
                                          float& bs0, float& bs1, float& bs2) {
    float b0 = bp[0], b1 = bp[1], b2 = bp[2];
    float b3 = bp[3], b4 = bp[4], b5 = bp[5];
    float vol = (b3 - b0) * (b4 - b1) * (b5 - b2);
    float s = cbrtf(vol);
    float lvl = floorf(4.0f + log2f(s / 160.0f) + 1e-6f);
    lvl = fminf(fmaxf(lvl, 2.0f), 5.0f);
    l = (int)lvl - 2;
    float scale;
    if (l == 0)      { dim = d0;  scale = 0.25f;    }
    else if (l == 1) { dim = d1;  scale = 0.125f;   }
    else if (l == 2) { dim = d2_; scale = 0.0625f;  }
    else             { dim = d3;  scale = 0.03125f; }
    fdim = (float)dim;
    st0 = b0 * scale; st1 = b1 * scale; st2 = b2 * scale;
    float e0 = fmaxf(b3 * scale - st0, 1.0f);
    float e1 = fmaxf(b4 * scale - st1, 1.0f);
    float e2 = fmaxf(b5 * scale - st2, 1.0f);
    bs0 = e0 * (1.0f / OUT); bs1 = e1 * (1.0f / OUT); bs2 = e2 * (1.0f / OUT);
}

// ---------------- fallback (R4-proven) ----------------
#define LDSF 11776
#define FBLK 512

__global__ __launch_bounds__(FBLK) void roi_align_fallback_kernel(
    const float* __restrict__ f0, const float* __restrict__ f1,
    const float* __restrict__ f2, const float* __restrict__ f3,
    const float* __restrict__ boxes, float* __restrict__ out,
    int N, int C, int d0, int d1, int d2_, int d3)
{
    __shared__ float lds[LDSF];
    const int c   = blockIdx.x;
    const int n   = blockIdx.y;
    const int tid = threadIdx.x;

    int l, dim; float fdim, st0, st1, st2, bs0, bs1, bs2;
    box_setup(boxes + n * 6, d0, d1, d2_, d3,
              l, dim, fdim, st0, st1, st2, bs0, bs1, bs2);
    const float* f = (l == 0) ? f0 : (l == 1) ? f1 : (l == 2) ? f2 : f3;

    const int dsq = dim * dim;
    const size_t dcube = (size_t)dim * dsq;
    const float* fc = f + (size_t)c * dcube;

    int x0 = (int)floorf(fminf(fmaxf(st0 + 0.25f * bs0, 0.0f), fdim - 1.0f));
    int x1 = min((int)floorf(fminf(fmaxf(st0 + 6.75f * bs0, 0.0f), fdim - 1.0f)) + 1, dim - 1);
    int y0 = (int)floorf(fminf(fmaxf(st1 + 0.25f * bs1, 0.0f), fdim - 1.0f));
    int y1 = min((int)floorf(fminf(fmaxf(st1 + 6.75f * bs1, 0.0f), fdim - 1.0f)) + 1, dim - 1);
    int z0 = (int)floorf(fminf(fmaxf(st2 + 0.25f * bs2, 0.0f), fdim - 1.0f));
    int z1 = min((int)floorf(fminf(fmaxf(st2 + 6.75f * bs2, 0.0f), fdim - 1.0f)) + 1, dim - 1);

    int nx = x1 - x0 + 1, ny = y1 - y0 + 1, nz = z1 - z0 + 1;
    int nzp = nz + 1;
    int nynzp = ny * nzp;
    int nrows = nx * ny;
    int nregp = nrows * nzp;

    int xl[2], yl[2], zl[2];
    float xw0[2], xw1[2], yw0[2], yw1[2], zw0[2], zw1[2];
    if (tid < NVOX) {
        int oz = tid % OUT;
        int oy = (tid / OUT) % OUT;
        int ox = tid / (OUT * OUT);
        #pragma unroll
        for (int r = 0; r < 2; ++r) {
            float off = 0.25f + 0.5f * (float)r;
            axis_samp(st0 + ((float)ox + off) * bs0, fdim, dim, xl[r], xw0[r], xw1[r]);
            axis_samp(st1 + ((float)oy + off) * bs1, fdim, dim, yl[r], yw0[r], yw1[r]);
            axis_samp(st2 + ((float)oz + off) * bs2, fdim, dim, zl[r], zw0[r], zw1[r]);
        }
    }

    if (nregp <= LDSF) {
        float rnzp = 1.0f / (float)nzp;
        float rny  = 1.0f / (float)ny;
        for (int e = tid; e < nregp; e += FBLK) {
            int row = (int)((float)e * rnzp);
            int zz = e - row * nzp;
            if (zz < 0)        { row -= 1; zz += nzp; }
            else if (zz >= nzp){ row += 1; zz -= nzp; }
            int rx = (int)((float)row * rny);
            int ry = row - rx * ny;
            if (ry < 0)        { rx -= 1; ry += ny; }
            else if (ry >= ny) { rx += 1; ry -= ny; }
            int zsrc = min(zz, nz - 1);
            lds[e] = fc[((size_t)(x0 + rx) * dim + (y0 + ry)) * dim + (z0 + zsrc)];
        }
        __syncthreads();

        if (tid < NVOX) {
            int XL[2], XH[2], YL[2], YH[2], ZL[2];
            #pragma unroll
            for (int r = 0; r < 2; ++r) {
                XL[r] = (xl[r] - x0) * nynzp;
                XH[r] = (min(xl[r] + 1, dim - 1) - x0) * nynzp;
                YL[r] = (yl[r] - y0) * nzp;
                YH[r] = (min(yl[r] + 1, dim - 1) - y0) * nzp;
                ZL[r] = zl[r] - z0;
            }
            float acc = 0.0f;
            #pragma unroll
            for (int rx2 = 0; rx2 < 2; ++rx2) {
                #pragma unroll
                for (int ry2 = 0; ry2 < 2; ++ry2) {
                    #pragma unroll
                    for (int rz2 = 0; rz2 < 2; ++rz2) {
                        const float* pll = lds + (XL[rx2] + YL[ry2] + ZL[rz2]);
                        const float* plh = lds + (XL[rx2] + YH[ry2] + ZL[rz2]);
                        const float* phl = lds + (XH[rx2] + YL[ry2] + ZL[rz2]);
                        const float* phh = lds + (XH[rx2] + YH[ry2] + ZL[rz2]);
                        float wz0 = zw0[rz2], wz1 = zw1[rz2];
                        float vx0 = yw0[ry2] * (wz0 * pll[0] + wz1 * pll[1])
                                  + yw1[ry2] * (wz0 * plh[0] + wz1 * plh[1]);
                        float vx1 = yw0[ry2] * (wz0 * phl[0] + wz1 * phl[1])
                                  + yw1[ry2] * (wz0 * phh[0] + wz1 * phh[1]);
                        acc += xw0[rx2] * vx0 + xw1[rx2] * vx1;
                    }
                }
            }
            out[((size_t)n * C + c) * NVOX + tid] = acc * 0.125f;
        }
    } else {
        if (tid < NVOX) {
            float acc = 0.0f;
            #pragma unroll
            for (int rx2 = 0; rx2 < 2; ++rx2) {
                const float* pxl = fc + (size_t)xl[rx2] * dsq;
                const float* pxh = fc + (size_t)min(xl[rx2] + 1, dim - 1) * dsq;
                float wx0 = xw0[rx2], wx1 = xw1[rx2];
                #pragma unroll
                for (int ry2 = 0; ry2 < 2; ++ry2) {
                    int ryl = yl[ry2] * dim;
                    int ryh = min(yl[ry2] + 1, dim - 1) * dim;
                    float wy0 = yw0[ry2], wy1 = yw1[ry2];
                    #pragma unroll
                    for (int rz2 = 0; rz2 < 2; ++rz2) {
                        int bZL = zl[rz2], bZH = min(zl[rz2] + 1, dim - 1);
                        float wz0 = zw0[rz2], wz1 = zw1[rz2];
                        float vx0 = wy0 * (wz0 * pxl[ryl + bZL] + wz1 * pxl[ryl + bZH])
                                  + wy1 * (wz0 * pxl[ryh + bZL] + wz1 * pxl[ryh + bZH]);
                        float vx1 = wy0 * (wz0 * pxh[ryl + bZL] + wz1 * pxh[ryl + bZH])
                                  + wy1 * (wz0 * pxh[ryh + bZL] + wz1 * pxh[ryh + bZH]);
                        acc += wx0 * vx0 + wx1 * vx1;
                    }
                }
            }
            out[((size_t)n * C + c) * NVOX + tid] = acc * 0.125f;
        }
    }
}

// ---------------- fused transpose: f32 (C,S) -> bf16 (S,C), all levels ----------------
__global__ __launch_bounds__(256) void transpose_bf16_kernel(
    const float* __restrict__ f0, const float* __restrict__ f1,
    const float* __restrict__ f2, const float* __restrict__ f3,
    u16* __restrict__ ws,
    int t1, int t2, int t3,              // cumulative tile counts for levels 0..2
    long S0, long S1, long S2, long S3,
    long off0, long off1, long off2, long off3)
{
    __shared__ u16 tile[64 * 65];
    int b = blockIdx.x;
    const float* src; u16* dst; long S; int tloc;
    if (b < t1)      { src = f0; dst = ws + off0; S = S0; tloc = b; }
    else if (b < t2) { src = f1; dst = ws + off1; S = S1; tloc = b - t1; }
    else if (b < t3) { src = f2; dst = ws + off2; S = S2; tloc = b - t2; }
    else             { src = f3; dst = ws + off3; S = S3; tloc = b - t3; }

    long s0 = (long)tloc * 64;
    int lane  = threadIdx.x & 63;
    int chunk = threadIdx.x >> 6;    // 0..3
    #pragma unroll
    for (int k = 0; k < 16; ++k) {
        int ch = chunk * 16 + k;
        tile[lane * 65 + ch] = f32_to_bf16(src[(size_t)ch * S + s0 + lane]);
    }
    __syncthreads();
    #pragma unroll
    for (int k = 0; k < 16; ++k) {
        int s = chunk * 16 + k;
        dst[(s0 + s) * 64 + lane] = tile[s * 65 + lane];
    }
}

// ---------------- main gather: channel-last bf16, x-plane blocks ----------------
// Block = one ox-plane of one box: 49 voxels (+7 null slots), 448 threads (7 waves),
// grid = N*7 with XCD swizzle (all 7 planes of box n -> XCD n%8). Fewer, longer
// blocks amortize box_setup/sort/barriers 1.53x vs the 32-voxel version, and the
// block footprint is a single 2-3-cell x-slab -> tighter L2 reuse.
//
// tid = slot*8 + oct; oct = channel group (8 lanes/sample, 8 ch each, 16B loads).
// Phase A (lanes 0-167): lane (s = tid%56, a = tid/56) merges axis a of voxel s
//   (null for s>=49: axm=0). Only these lanes run box_setup (cbrtf/log2f).
// Rank sort: 56 slots ranked by padded list length; null slots (len 0) sink to
//   the low ranks and are absorbed by the balance. Lane-group g serves rank-g slot.
// Phase B: compacted (byte-off, w) list, zero-padded to wave max (mult of 4);
//   same lanes write & read a slot's list -> no barrier before main.
// Main: depth-2 self-renaming pipeline; direct global stores (slot<49 only).

#define LSTRIDE 66        // int2 stride per slot: 528 B (16B-aligned; wave-slots on distinct banks)

struct Grp8 { float w0, w1, w2, w3; uint4 v0, v1, v2, v3; };

__device__ __forceinline__ Grp8 issue_grp8(const int2* L, int g,
                                           const char* base, int qoff) {
    int4 a = *(const int4*)(L + (g << 2));
    int4 b = *(const int4*)(L + (g << 2) + 2);
    Grp8 r;
    r.w0 = __int_as_float(a.y); r.v0 = *(const uint4*)(base + (a.x + qoff));
    r.w1 = __int_as_float(a.w); r.v1 = *(const uint4*)(base + (a.z + qoff));
    r.w2 = __int_as_float(b.y); r.v2 = *(const uint4*)(base + (b.x + qoff));
    r.w3 = __int_as_float(b.w); r.v3 = *(const uint4*)(base + (b.z + qoff));
    return r;
}

// one packed u32 = {even ch in low 16, odd ch in high 16}
#define ACC2(u, w, aE, aO)                                          \
    aE = fmaf(w, __uint_as_float((u) << 16), aE);                   \
    aO = fmaf(w, __uint_as_float((u) & 0xffff0000u), aO);

__device__ __forceinline__ void consume_grp8(const Grp8& g, float4& a0, float4& a1) {
    ACC2(g.v0.x, g.w0, a0.x, a0.y)  ACC2(g.v0.y, g.w0, a0.z, a0.w)
    ACC2(g.v0.z, g.w0, a1.x, a1.y)  ACC2(g.v0.w, g.w0, a1.z, a1.w)
    ACC2(g.v1.x, g.w1, a0.x, a0.y)  ACC2(g.v1.y, g.w1, a0.z, a0.w)
    ACC2(g.v1.z, g.w1, a1.x, a1.y)  ACC2(g.v1.w, g.w1, a1.z, a1.w)
    ACC2(g.v2.x, g.w2, a0.x, a0.y)  ACC2(g.v2.y, g.w2, a0.z, a0.w)
    ACC2(g.v2.z, g.w2, a1.x, a1.y)  ACC2(g.v2.w, g.w2, a1.z, a1.w)
    ACC2(g.v3.x, g.w3, a0.x, a0.y)  ACC2(g.v3.y, g.w3, a0.z, a0.w)
    ACC2(g.v3.z, g.w3, a1.x, a1.y)  ACC2(g.v3.w, g.w3, a1.z, a1.w)
}

__global__ __launch_bounds__(TPB, 4) void roi_align_cl_kernel(
    const u16* __restrict__ ws, const float* __restrict__ boxes,
    float* __restrict__ out, int N, int C,
    int d0, int d1, int d2_, int d3,
    long off0, long off1, long off2, long off3)
{
    __shared__ __align__(16) int2 lst[VSLOT * LSTRIDE];  // 29568 B
    __shared__ int2  awo[VSLOT][3][4];    // {premul byte-off, weight-bits}  5376 B
    __shared__ int   axm[VSLOT][3];       // per-axis merged counts           672 B
    __shared__ int   nTs[VSLOT];          // padded list length per slot
    __shared__ int   inv[VSLOT];          // inv[rank] = slot
    __shared__ int   bxl[1];              // level broadcast

    // ---- XCD-locality swizzle: all 7 planes of box n -> XCD n%8 ----
    const int bid   = blockIdx.x;
    const int q     = bid >> 3;
    const int rxcd  = bid & 7;
    const int qd    = q / NCHP;          // box group
    const int ox    = q - qd * NCHP;     // 0..6 (x-plane)
    const int n     = qd * 8 + rxcd;     // box
    if (n >= N) return;                  // block-uniform, before any barrier

    const int tid  = threadIdx.x;
    const int oct  = tid & 7;          // channel-group lane (8 ch each)
    const int slot = tid >> 3;         // 0..55 (rank position of this lane group)

    // ---- phase A: per-(voxel,axis) merge (lanes 0-167; only these run box_setup) ----
    if (tid < 3 * VSLOT) {
        const int s = tid % VSLOT;
        const int a = tid / VSLOT;           // 0,1,2
        if (s < VREAL) {
            int l, dim; float fdim, st0, st1, st2, bs0, bs1, bs2;
            box_setup(boxes + n * 6, d0, d1, d2_, d3,
                      l, dim, fdim, st0, st1, st2, bs0, bs1, bs2);
            if (tid == 0) bxl[0] = l;
            const int dsq = dim * dim;

            const int o1 = s / OUT;          // oy
            const int o2 = s - o1 * OUT;     // oz
            const int   strB = (a == 0) ? dsq * 128 : (a == 1) ? dim * 128 : 128;
            const float oA   = (a == 0) ? (float)ox : (a == 1) ? (float)o1 : (float)o2;
            const float sA   = (a == 0) ? st0 : (a == 1) ? st1 : st2;
            const float bA   = (a == 0) ? bs0 : (a == 1) ? bs1 : bs2;
            const float sc   = (a == 0) ? 0.125f : 1.0f;   // fold final /8 into x weights

            int lo0, lo1; float w00, w01, w10, w11;
            axis_samp(sA + (oA + 0.25f) * bA, fdim, dim, lo0, w00, w01);
            axis_samp(sA + (oA + 0.75f) * bA, fdim, dim, lo1, w10, w11);
            int hi0 = min(lo0 + 1, dim - 1);
            int hi1 = min(lo1 + 1, dim - 1);
            // sorted order: lo0 <= min(hi0,lo1) <= max(hi0,lo1) <= hi1  (lo1 >= lo0)
            int sa, sb; float qa, qb;
            if (hi0 <= lo1) { sa = hi0; qa = w01; sb = lo1; qb = w10; }
            else            { sa = lo1; qa = w10; sb = hi0; qb = w01; }
            int m = 0;
            int cur = lo0; float wacc = w00;
            if (sa == cur) wacc += qa;
            else {
                if (wacc > 0.0f) { awo[s][a][m] = make_int2(cur * strB, __float_as_int(wacc * sc)); ++m; }
                cur = sa; wacc = qa;
            }
            if (sb == cur) wacc += qb;
            else {
                if (wacc > 0.0f) { awo[s][a][m] = make_int2(cur * strB, __float_as_int(wacc * sc)); ++m; }
                cur = sb; wacc = qb;
            }
            if (hi1 == cur) wacc += w11;
            else {
                if (wacc > 0.0f) { awo[s][a][m] = make_int2(cur * strB, __float_as_int(wacc * sc)); ++m; }
                cur = hi1; wacc = w11;
            }
            if (wacc > 0.0f) { awo[s][a][m] = make_int2(cur * strB, __float_as_int(wacc * sc)); ++m; }
            axm[s][a] = m;
        } else {
            axm[s][a] = 0;                   // null slot
        }
    }
    __syncthreads();

    // ---- rank sort: inv[rank] = slot, key = (nT4, slot) ----
    if (tid < VSLOT) {
        int nT = axm[tid][0] * axm[tid][1] * axm[tid][2];
        nTs[tid] = (nT + 3) & ~3;            // pad to multiple of 4 (0 for null)
    }
    __syncthreads();
    if (tid < VSLOT) {
        const int mykey = (nTs[tid] << 6) | tid;
        int r = 0;
        #pragma unroll
        for (int s = 0; s < VSLOT; ++s)
            r += (((nTs[s] << 6) | s) < mykey) ? 1 : 0;
        inv[r] = tid;
    }
    __syncthreads();

    const int myslot = inv[slot];            // assigned voxel slot (balanced)

    // ---- phase B: header + compacted list for the ASSIGNED slot ----
    const int l = bxl[0];
    const long loff = (l == 0) ? off0 : (l == 1) ? off1 : (l == 2) ? off2 : off3;
    int NTw;
    {
        const int mx = axm[myslot][0], my = axm[myslot][1], mz = axm[myslot][2];
        const int myz = my * mz;
        const int nT  = mx * myz;
        int nT4 = nTs[myslot];
        int m1  = max(nT4, __shfl_xor(nT4, 8));
        m1      = max(m1,  __shfl_xor(m1, 16));
        NTw     = max(m1,  __shfl_xor(m1, 32));  // wave-uniform max over its 8 slots
        const float rYZ = __builtin_amdgcn_rcpf((float)max(myz, 1));
        const float rZ  = __builtin_amdgcn_rcpf((float)max(mz, 1));
        for (int t = oct; t < NTw; t += 8) {
            int off = 0; float w = 0.0f;
            if (t < nT) {
                int i   = (int)(((float)t + 0.5f) * rYZ);
                int rem = t - i * myz;
                int j   = (int)(((float)rem + 0.5f) * rZ);
                int k   = rem - j * mz;
                int2 ei = awo[myslot][0][i];
                int2 ej = awo[myslot][1][j];
                int2 ek = awo[myslot][2][k];
                w   = __int_as_float(ei.y) * __int_as_float(ej.y) * __int_as_float(ek.y);
                off = ei.x + ej.x + ek.x;
            }
            lst[myslot * LSTRIDE + t] = make_int2(off, __float_as_int(w));
        }
    }
    // no barrier: a slot's list is written and read by the same 8 lanes (same wave)

    // ---- main gather: depth-2 self-renaming pipeline, wave-uniform NG ----
    float4 a0 = { 0.f, 0.f, 0.f, 0.f };
    float4 a1 = { 0.f, 0.f, 0.f, 0.f };
    {
        const char* base = (const char*)(ws + loff);   // block-uniform -> SGPR base
        const int qoff   = oct * 16;                   // 8 channels * 2B
        const int2* L    = lst + myslot * LSTRIDE;
        const int NG     = NTw >> 2;
        if (NG >= 1) {
            Grp8 A = issue_grp8(L, 0, base, qoff);
            int g = 1;
            for (; g + 1 < NG; g += 2) {
                Grp8 B = issue_grp8(L, g, base, qoff);
                consume_grp8(A, a0, a1);
                A = issue_grp8(L, g + 1, base, qoff);
                consume_grp8(B, a0, a1);
            }
            if (g < NG) {                              // one trailing group
                Grp8 B = issue_grp8(L, g, base, qoff);
                consume_grp8(A, a0, a1);
                consume_grp8(B, a0, a1);
            } else {
                consume_grp8(A, a0, a1);
            }
        }
    }

    // ---- epilogue: direct global stores (lane owns ch oct*8 .. oct*8+7) ----
    if (myslot < VREAL) {
        const int vox = ox * VREAL + myslot;
        float* op = out + (size_t)n * C * NVOX + (size_t)(oct * 8) * NVOX + vox;
        op[0 * NVOX] = a0.x;  op[1 * NVOX] = a0.y;
        op[2 * NVOX] = a0.z;  op[3 * NVOX] = a0.w;
        op[4 * NVOX] = a1.x;  op[5 * NVOX] = a1.y;
        op[6 * NVOX] = a1.z;  op[7 * NVOX] = a1.w;
    }
}

extern "C" void kernel_launch(void* const* d_in, const int* in_sizes, int n_in,
                              void* d_out, int out_size, void* d_ws, size_t ws_size,
                              hipStream_t stream) {
    const float* f0 = (const float*)d_in[0];
    const float* f1 = (const float*)d_in[1];
    const float* f2 = (const float*)d_in[2];
    const float* f3 = (const float*)d_in[3];
    const float* boxes = (const float*)d_in[4];
    float* out = (float*)d_out;

    int N = in_sizes[4] / 6;
    int C = out_size / (N * NVOX);

    auto cdim = [&](int sz) {
        int per_c = sz / C;
        return (int)(cbrtf((float)per_c) + 0.5f);
    };
    int d0 = cdim(in_sizes[0]);
    int d1 = cdim(in_sizes[1]);
    int d2 = cdim(in_sizes[2]);
    int d3 = cdim(in_sizes[3]);

    long S0 = (long)d0 * d0 * d0, S1 = (long)d1 * d1 * d1;
    long S2 = (long)d2 * d2 * d2, S3 = (long)d3 * d3 * d3;
    long off0 = 0, off1 = S0 * C, off2 = off1 + S1 * C, off3 = off2 + S2 * C;
    size_t need = (size_t)(off3 + S3 * C) * sizeof(u16);

    bool fast = (C == 64) && (ws_size >= need) &&
                (S0 % 64 == 0) && (S1 % 64 == 0) && (S2 % 64 == 0) && (S3 % 64 == 0);

    if (fast) {
        u16* ws = (u16*)d_ws;
        int t1 = (int)(S0 / 64);
        int t2 = t1 + (int)(S1 / 64);
        int t3 = t2 + (int)(S2 / 64);
        int tt = t3 + (int)(S3 / 64);
        transpose_bf16_kernel<<<tt, 256, 0, stream>>>(f0, f1, f2, f3, ws,
                                                      t1, t2, t3,
                                                      S0, S1, S2, S3,
                                                      off0, off1, off2, off3);
        int nb8 = ((N + 7) / 8) * 8;           // swizzle block count (bijective for N%8==0)
        int nblk = nb8 * NCHP;
        roi_align_cl_kernel<<<nblk, TPB, 0, stream>>>(ws, boxes, out, N, C,
                                                      d0, d1, d2, d3,
                                                      off0, off1, off2, off3);
    } else {
        dim3 grid(C, N);
        roi_align_fallback_kernel<<<grid, FBLK, 0, stream>>>(f0, f1, f2, f3, boxes, out,
                                                             N, C, d0, d1, d2, d3);
    }
}

// Round 10
// 140.421 us; speedup vs baseline: 1.0372x; 1.0372x over previous
//
#include <hip/hip_runtime.h>
#include <math.h>

#define OUT 7
#define NVOX 343          // 7*7*7
#define VB 32             // voxels per block (fast path)
#define NCH2 11           // ceil(343/32)

typedef unsigned short u16;
typedef unsigned int u32;

__device__ __forceinline__ u16 f32_to_bf16(float f) {
    u32 u = __float_as_uint(f);
    u32 r = (u + 0x7fffu + ((u >> 16) & 1u)) >> 16;   // RNE
    return (u16)r;
}
__device__ __forceinline__ float bf16_to_f32(u16 h) {
    return __uint_as_float(((u32)h) << 16);
}

__device__ __forceinline__ void axis_samp(float c, float fdim, int dim,
                                          int& lo, float& w0, float& w1) {
    float valid = (c > -1.0f && c < fdim) ? 1.0f : 0.0f;
    float cc = fminf(fmaxf(c, 0.0f), fdim - 1.0f);
    lo = (int)floorf(cc);
    float fr = cc - (float)lo;
    w0 = (1.0f - fr) * valid;
    w1 = fr * valid;     // == 0 whenever hi would clamp
}

__device__ __forceinline__ void box_setup(const float* bp,
                                          int d0, int d1, int d2_, int d3,
                                          int& l, int& dim, float& fdim,
                                          float& st0, float& st1, float& st2,
                                          float& bs0, float& bs1, float& bs2) {
    float b0 = bp[0], b1 = bp[1], b2 = bp[2];
    float b3 = bp[3], b4 = bp[4], b5 = bp[5];
    float vol = (b3 - b0) * (b4 - b1) * (b5 - b2);
    float s = cbrtf(vol);
    float lvl = floorf(4.0f + log2f(s / 160.0f) + 1e-6f);
    lvl = fminf(fmaxf(lvl, 2.0f), 5.0f);
    l = (int)lvl - 2;
    float scale;
    if (l == 0)      { dim = d0;  scale = 0.25f;    }
    else if (l == 1) { dim = d1;  scale = 0.125f;   }
    else if (l == 2) { dim = d2_; scale = 0.0625f;  }
    else             { dim = d3;  scale = 0.03125f; }
    fdim = (float)dim;
    st0 = b0 * scale; st1 = b1 * scale; st2 = b2 * scale;
    float e0 = fmaxf(b3 * scale - st0, 1.0f);
    float e1 = fmaxf(b4 * scale - st1, 1.0f);
    float e2 = fmaxf(b5 * scale - st2, 1.0f);
    bs0 = e0 * (1.0f / OUT); bs1 = e1 * (1.0f / OUT); bs2 = e2 * (1.0f / OUT);
}

// ---------------- fallback (R4-proven) ----------------
#define LDSF 11776
#define FBLK 512

__global__ __launch_bounds__(FBLK) void roi_align_fallback_kernel(
    const float* __restrict__ f0, const float* __restrict__ f1,
    const float* __restrict__ f2, const float* __restrict__ f3,
    const float* __restrict__ boxes, float* __restrict__ out,
    int N, int C, int d0, int d1, int d2_, int d3)
{
    __shared__ float lds[LDSF];
    const int c   = blockIdx.x;
    const int n   = blockIdx.y;
    const int tid = threadIdx.x;

    int l, dim; float fdim, st0, st1, st2, bs0, bs1, bs2;
    box_setup(boxes + n * 6, d0, d1, d2_, d3,
              l, dim, fdim, st0, st1, st2, bs0, bs1, bs2);
    const float* f = (l == 0) ? f0 : (l == 1) ? f1 : (l == 2) ? f2 : f3;

    const int dsq = dim * dim;
    const size_t dcube = (size_t)dim * dsq;
    const float* fc = f + (size_t)c * dcube;

    int x0 = (int)floorf(fminf(fmaxf(st0 + 0.25f * bs0, 0.0f), fdim - 1.0f));
    int x1 = min((int)floorf(fminf(fmaxf(st0 + 6.75f * bs0, 0.0f), fdim - 1.0f)) + 1, dim - 1);
    int y0 = (int)floorf(fminf(fmaxf(st1 + 0.25f * bs1, 0.0f), fdim - 1.0f));
    int y1 = min((int)floorf(fminf(fmaxf(st1 + 6.75f * bs1, 0.0f), fdim - 1.0f)) + 1, dim - 1);
    int z0 = (int)floorf(fminf(fmaxf(st2 + 0.25f * bs2, 0.0f), fdim - 1.0f));
    int z1 = min((int)floorf(fminf(fmaxf(st2 + 6.75f * bs2, 0.0f), fdim - 1.0f)) + 1, dim - 1);

    int nx = x1 - x0 + 1, ny = y1 - y0 + 1, nz = z1 - z0 + 1;
    int nzp = nz + 1;
    int nynzp = ny * nzp;
    int nrows = nx * ny;
    int nregp = nrows * nzp;

    int xl[2], yl[2], zl[2];
    float xw0[2], xw1[2], yw0[2], yw1[2], zw0[2], zw1[2];
    if (tid < NVOX) {
        int oz = tid % OUT;
        int oy = (tid / OUT) % OUT;
        int ox = tid / (OUT * OUT);
        #pragma unroll
        for (int r = 0; r < 2; ++r) {
            float off = 0.25f + 0.5f * (float)r;
            axis_samp(st0 + ((float)ox + off) * bs0, fdim, dim, xl[r], xw0[r], xw1[r]);
            axis_samp(st1 + ((float)oy + off) * bs1, fdim, dim, yl[r], yw0[r], yw1[r]);
            axis_samp(st2 + ((float)oz + off) * bs2, fdim, dim, zl[r], zw0[r], zw1[r]);
        }
    }

    if (nregp <= LDSF) {
        float rnzp = 1.0f / (float)nzp;
        float rny  = 1.0f / (float)ny;
        for (int e = tid; e < nregp; e += FBLK) {
            int row = (int)((float)e * rnzp);
            int zz = e - row * nzp;
            if (zz < 0)        { row -= 1; zz += nzp; }
            else if (zz >= nzp){ row += 1; zz -= nzp; }
            int rx = (int)((float)row * rny);
            int ry = row - rx * ny;
            if (ry < 0)        { rx -= 1; ry += ny; }
            else if (ry >= ny) { rx += 1; ry -= ny; }
            int zsrc = min(zz, nz - 1);
            lds[e] = fc[((size_t)(x0 + rx) * dim + (y0 + ry)) * dim + (z0 + zsrc)];
        }
        __syncthreads();

        if (tid < NVOX) {
            int XL[2], XH[2], YL[2], YH[2], ZL[2];
            #pragma unroll
            for (int r = 0; r < 2; ++r) {
                XL[r] = (xl[r] - x0) * nynzp;
                XH[r] = (min(xl[r] + 1, dim - 1) - x0) * nynzp;
                YL[r] = (yl[r] - y0) * nzp;
                YH[r] = (min(yl[r] + 1, dim - 1) - y0) * nzp;
                ZL[r] = zl[r] - z0;
            }
            float acc = 0.0f;
            #pragma unroll
            for (int rx2 = 0; rx2 < 2; ++rx2) {
                #pragma unroll
                for (int ry2 = 0; ry2 < 2; ++ry2) {
                    #pragma unroll
                    for (int rz2 = 0; rz2 < 2; ++rz2) {
                        const float* pll = lds + (XL[rx2] + YL[ry2] + ZL[rz2]);
                        const float* plh = lds + (XL[rx2] + YH[ry2] + ZL[rz2]);
                        const float* phl = lds + (XH[rx2] + YL[ry2] + ZL[rz2]);
                        const float* phh = lds + (XH[rx2] + YH[ry2] + ZL[rz2]);
                        float wz0 = zw0[rz2], wz1 = zw1[rz2];
                        float vx0 = yw0[ry2] * (wz0 * pll[0] + wz1 * pll[1])
                                  + yw1[ry2] * (wz0 * plh[0] + wz1 * plh[1]);
                        float vx1 = yw0[ry2] * (wz0 * phl[0] + wz1 * phl[1])
                                  + yw1[ry2] * (wz0 * phh[0] + wz1 * phh[1]);
                        acc += xw0[rx2] * vx0 + xw1[rx2] * vx1;
                    }
                }
            }
            out[((size_t)n * C + c) * NVOX + tid] = acc * 0.125f;
        }
    } else {
        if (tid < NVOX) {
            float acc = 0.0f;
            #pragma unroll
            for (int rx2 = 0; rx2 < 2; ++rx2) {
                const float* pxl = fc + (size_t)xl[rx2] * dsq;
                const float* pxh = fc + (size_t)min(xl[rx2] + 1, dim - 1) * dsq;
                float wx0 = xw0[rx2], wx1 = xw1[rx2];
                #pragma unroll
                for (int ry2 = 0; ry2 < 2; ++ry2) {
                    int ryl = yl[ry2] * dim;
                    int ryh = min(yl[ry2] + 1, dim - 1) * dim;
                    float wy0 = yw0[ry2], wy1 = yw1[ry2];
                    #pragma unroll
                    for (int rz2 = 0; rz2 < 2; ++rz2) {
                        int bZL = zl[rz2], bZH = min(zl[rz2] + 1, dim - 1);
                        float wz0 = zw0[rz2], wz1 = zw1[rz2];
                        float vx0 = wy0 * (wz0 * pxl[ryl + bZL] + wz1 * pxl[ryl + bZH])
                                  + wy1 * (wz0 * pxl[ryh + bZL] + wz1 * pxl[ryh + bZH]);
                        float vx1 = wy0 * (wz0 * pxh[ryl + bZL] + wz1 * pxh[ryl + bZH])
                                  + wy1 * (wz0 * pxh[ryh + bZL] + wz1 * pxh[ryh + bZH]);
                        acc += wx0 * vx0 + wx1 * vx1;
                    }
                }
            }
            out[((size_t)n * C + c) * NVOX + tid] = acc * 0.125f;
        }
    }
}

// ---------------- fused transpose: f32 (C,S) -> bf16 (S,C), all levels ----------------
__global__ __launch_bounds__(256) void transpose_bf16_kernel(
    const float* __restrict__ f0, const float* __restrict__ f1,
    const float* __restrict__ f2, const float* __restrict__ f3,
    u16* __restrict__ ws,
    int t1, int t2, int t3,              // cumulative tile counts for levels 0..2
    long S0, long S1, long S2, long S3,
    long off0, long off1, long off2, long off3)
{
    __shared__ u16 tile[64 * 65];
    int b = blockIdx.x;
    const float* src; u16* dst; long S; int tloc;
    if (b < t1)      { src = f0; dst = ws + off0; S = S0; tloc = b; }
    else if (b < t2) { src = f1; dst = ws + off1; S = S1; tloc = b - t1; }
    else if (b < t3) { src = f2; dst = ws + off2; S = S2; tloc = b - t2; }
    else             { src = f3; dst = ws + off3; S = S3; tloc = b - t3; }

    long s0 = (long)tloc * 64;
    int lane  = threadIdx.x & 63;
    int chunk = threadIdx.x >> 6;    // 0..3
    #pragma unroll
    for (int k = 0; k < 16; ++k) {
        int ch = chunk * 16 + k;
        tile[lane * 65 + ch] = f32_to_bf16(src[(size_t)ch * S + s0 + lane]);
    }
    __syncthreads();
    #pragma unroll
    for (int k = 0; k < 16; ++k) {
        int s = chunk * 16 + k;
        dst[(s0 + s) * 64 + lane] = tile[s * 65 + lane];
    }
}

// ---------------- main gather: channel-last bf16, dedup'd + XCD-swizzled ----------------
// 1D grid, XCD-locality swizzle: bid = (n&7) + 8*(chunk + 11*(n>>3)).
// Under round-robin block->XCD dispatch, ALL 11 chunks of box n land on XCD n%8,
// so the box's gather footprint (~0.1-0.4 MB) is pulled into that XCD's 4MB L2
// once instead of 11x from L3 (level-0 ws = 33.5MB >> 4MB L2).
//
// 256 threads; tid = slot*8 + oct; oct = channel group (8 lanes/sample, 8 ch each
// -> 16B ushort8 loads).
// Phase A (lanes 0-95): lane (s,a) merges axis a of voxel s: 4 taps -> <=4
//   distinct (cell, summed-weight) pairs; only these lanes run box_setup.
// Rank sort: slots ranked by padded list length; lane-group g serves rank-g slot.
// Phase B: compacted (byte-off, w) list, zero-padded to wave max (mult of 4).
// Main: depth-2 self-renaming pipeline; direct global stores.

#define LSTRIDE 66        // int2 stride per slot: 528 B (16B-aligned; wave-slots on distinct banks)

struct Grp8 { float w0, w1, w2, w3; uint4 v0, v1, v2, v3; };

__device__ __forceinline__ Grp8 issue_grp8(const int2* L, int g,
                                           const char* base, int qoff) {
    int4 a = *(const int4*)(L + (g << 2));
    int4 b = *(const int4*)(L + (g << 2) + 2);
    Grp8 r;
    r.w0 = __int_as_float(a.y); r.v0 = *(const uint4*)(base + (a.x + qoff));
    r.w1 = __int_as_float(a.w); r.v1 = *(const uint4*)(base + (a.z + qoff));
    r.w2 = __int_as_float(b.y); r.v2 = *(const uint4*)(base + (b.x + qoff));
    r.w3 = __int_as_float(b.w); r.v3 = *(const uint4*)(base + (b.z + qoff));
    return r;
}

// one packed u32 = {even ch in low 16, odd ch in high 16}
#define ACC2(u, w, aE, aO)                                          \
    aE = fmaf(w, __uint_as_float((u) << 16), aE);                   \
    aO = fmaf(w, __uint_as_float((u) & 0xffff0000u), aO);

__device__ __forceinline__ void consume_grp8(const Grp8& g, float4& a0, float4& a1) {
    ACC2(g.v0.x, g.w0, a0.x, a0.y)  ACC2(g.v0.y, g.w0, a0.z, a0.w)
    ACC2(g.v0.z, g.w0, a1.x, a1.y)  ACC2(g.v0.w, g.w0, a1.z, a1.w)
    ACC2(g.v1.x, g.w1, a0.x, a0.y)  ACC2(g.v1.y, g.w1, a0.z, a0.w)
    ACC2(g.v1.z, g.w1, a1.x, a1.y)  ACC2(g.v1.w, g.w1, a1.z, a1.w)
    ACC2(g.v2.x, g.w2, a0.x, a0.y)  ACC2(g.v2.y, g.w2, a0.z, a0.w)
    ACC2(g.v2.z, g.w2, a1.x, a1.y)  ACC2(g.v2.w, g.w2, a1.z, a1.w)
    ACC2(g.v3.x, g.w3, a0.x, a0.y)  ACC2(g.v3.y, g.w3, a0.z, a0.w)
    ACC2(g.v3.z, g.w3, a1.x, a1.y)  ACC2(g.v3.w, g.w3, a1.z, a1.w)
}

__global__ __launch_bounds__(256, 4) void roi_align_cl_kernel(
    const u16* __restrict__ ws, const float* __restrict__ boxes,
    float* __restrict__ out, int N, int C,
    int d0, int d1, int d2_, int d3,
    long off0, long off1, long off2, long off3)
{
    __shared__ __align__(16) int2 lst[VB * LSTRIDE];  // 16896 B
    __shared__ int2  awo[VB][3][4];       // {premul byte-off, weight-bits}  3072 B
    __shared__ int   axm[VB][3];          // per-axis merged counts           384 B
    __shared__ int   nTs[VB];             // padded list length per slot
    __shared__ int   inv[VB];             // inv[rank] = slot
    __shared__ int   bxl[1];              // level broadcast

    // ---- XCD-locality swizzle: same-box chunks -> same XCD ----
    const int bid   = blockIdx.x;
    const int q     = bid >> 3;
    const int rxcd  = bid & 7;
    const int qd    = q / 11;            // box group
    const int chunk = q - qd * 11;       // 0..10
    const int n     = qd * 8 + rxcd;     // box
    if (n >= N) return;                  // block-uniform, before any barrier
    const int cb    = chunk * VB;        // chunk base voxel

    const int tid  = threadIdx.x;
    const int oct  = tid & 7;          // channel-group lane (8 ch each)
    const int slot = tid >> 3;         // 0..31 (rank position of this lane group)

    // ---- phase A: per-(voxel,axis) merge (lanes 0-95; only these run box_setup) ----
    if (tid < 96) {
        int l, dim; float fdim, st0, st1, st2, bs0, bs1, bs2;
        box_setup(boxes + n * 6, d0, d1, d2_, d3,
                  l, dim, fdim, st0, st1, st2, bs0, bs1, bs2);
        if (tid == 0) bxl[0] = l;
        const int dsq = dim * dim;

        const int s = tid & 31;
        const int a = tid >> 5;              // 0,1,2
        int v = min(cb + s, NVOX - 1);
        int o2 = v % OUT;
        int t7 = v / OUT;
        int o1 = t7 % OUT;
        int o0 = t7 / OUT;
        const int   strB = (a == 0) ? dsq * 128 : (a == 1) ? dim * 128 : 128;
        const float oA   = (a == 0) ? (float)o0 : (a == 1) ? (float)o1 : (float)o2;
        const float sA   = (a == 0) ? st0 : (a == 1) ? st1 : st2;
        const float bA   = (a == 0) ? bs0 : (a == 1) ? bs1 : bs2;
        const float sc   = (a == 0) ? 0.125f : 1.0f;   // fold final /8 into x weights

        int lo0, lo1; float w00, w01, w10, w11;
        axis_samp(sA + (oA + 0.25f) * bA, fdim, dim, lo0, w00, w01);
        axis_samp(sA + (oA + 0.75f) * bA, fdim, dim, lo1, w10, w11);
        int hi0 = min(lo0 + 1, dim - 1);
        int hi1 = min(lo1 + 1, dim - 1);
        // sorted order: lo0 <= min(hi0,lo1) <= max(hi0,lo1) <= hi1  (lo1 >= lo0)
        int sa, sb; float qa, qb;
        if (hi0 <= lo1) { sa = hi0; qa = w01; sb = lo1; qb = w10; }
        else            { sa = lo1; qa = w10; sb = hi0; qb = w01; }
        int m = 0;
        int cur = lo0; float wacc = w00;
        if (sa == cur) wacc += qa;
        else {
            if (wacc > 0.0f) { awo[s][a][m] = make_int2(cur * strB, __float_as_int(wacc * sc)); ++m; }
            cur = sa; wacc = qa;
        }
        if (sb == cur) wacc += qb;
        else {
            if (wacc > 0.0f) { awo[s][a][m] = make_int2(cur * strB, __float_as_int(wacc * sc)); ++m; }
            cur = sb; wacc = qb;
        }
        if (hi1 == cur) wacc += w11;
        else {
            if (wacc > 0.0f) { awo[s][a][m] = make_int2(cur * strB, __float_as_int(wacc * sc)); ++m; }
            cur = hi1; wacc = w11;
        }
        if (wacc > 0.0f) { awo[s][a][m] = make_int2(cur * strB, __float_as_int(wacc * sc)); ++m; }
        axm[s][a] = m;
    }
    __syncthreads();

    // ---- rank sort: inv[rank] = slot, key = (nT4, slot) ----
    if (tid < VB) {
        int nT = axm[tid][0] * axm[tid][1] * axm[tid][2];
        nTs[tid] = (nT + 3) & ~3;            // pad to multiple of 4
    }
    __syncthreads();
    if (tid < VB) {
        const int mykey = (nTs[tid] << 6) | tid;
        int r = 0;
        #pragma unroll
        for (int s = 0; s < VB; ++s)
            r += (((nTs[s] << 6) | s) < mykey) ? 1 : 0;
        inv[r] = tid;
    }
    __syncthreads();

    const int myslot = inv[slot];            // assigned voxel slot (balanced)

    // ---- phase B: header + compacted list for the ASSIGNED slot ----
    const int l = bxl[0];
    const long loff = (l == 0) ? off0 : (l == 1) ? off1 : (l == 2) ? off2 : off3;
    int NTw;
    {
        const int mx = axm[myslot][0], my = axm[myslot][1], mz = axm[myslot][2];
        const int myz = my * mz;
        const int nT  = mx * myz;
        int nT4 = nTs[myslot];
        int m1  = max(nT4, __shfl_xor(nT4, 8));
        m1      = max(m1,  __shfl_xor(m1, 16));
        NTw     = max(m1,  __shfl_xor(m1, 32));  // wave-uniform max over its 8 slots
        const float rYZ = __builtin_amdgcn_rcpf((float)max(myz, 1));
        const float rZ  = __builtin_amdgcn_rcpf((float)max(mz, 1));
        for (int t = oct; t < NTw; t += 8) {
            int off = 0; float w = 0.0f;
            if (t < nT) {
                int i   = (int)(((float)t + 0.5f) * rYZ);
                int rem = t - i * myz;
                int j   = (int)(((float)rem + 0.5f) * rZ);
                int k   = rem - j * mz;
                int2 ei = awo[myslot][0][i];
                int2 ej = awo[myslot][1][j];
                int2 ek = awo[myslot][2][k];
                w   = __int_as_float(ei.y) * __int_as_float(ej.y) * __int_as_float(ek.y);
                off = ei.x + ej.x + ek.x;
            }
            lst[myslot * LSTRIDE + t] = make_int2(off, __float_as_int(w));
        }
    }
    // no barrier: a slot's list is written and read by the same 8 lanes (same wave)

    // ---- main gather: depth-2 self-renaming pipeline, wave-uniform NG ----
    float4 a0 = { 0.f, 0.f, 0.f, 0.f };
    float4 a1 = { 0.f, 0.f, 0.f, 0.f };
    {
        const char* base = (const char*)(ws + loff);   // block-uniform -> SGPR base
        const int qoff   = oct * 16;                   // 8 channels * 2B
        const int2* L    = lst + myslot * LSTRIDE;
        const int NG     = NTw >> 2;
        if (NG >= 1) {
            Grp8 A = issue_grp8(L, 0, base, qoff);
            int g = 1;
            for (; g + 1 < NG; g += 2) {
                Grp8 B = issue_grp8(L, g, base, qoff);
                consume_grp8(A, a0, a1);
                A = issue_grp8(L, g + 1, base, qoff);
                consume_grp8(B, a0, a1);
            }
            if (g < NG) {                              // one trailing group
                Grp8 B = issue_grp8(L, g, base, qoff);
                consume_grp8(A, a0, a1);
                consume_grp8(B, a0, a1);
            } else {
                consume_grp8(A, a0, a1);
            }
        }
    }

    // ---- epilogue: direct global stores (lane owns ch oct*8 .. oct*8+7) ----
    const int vox = cb + myslot;
    if (vox < NVOX) {
        float* op = out + (size_t)n * C * NVOX + (size_t)(oct * 8) * NVOX + vox;
        op[0 * NVOX] = a0.x;  op[1 * NVOX] = a0.y;
        op[2 * NVOX] = a0.z;  op[3 * NVOX] = a0.w;
        op[4 * NVOX] = a1.x;  op[5 * NVOX] = a1.y;
        op[6 * NVOX] = a1.z;  op[7 * NVOX] = a1.w;
    }
}

extern "C" void kernel_launch(void* const* d_in, const int* in_sizes, int n_in,
                              void* d_out, int out_size, void* d_ws, size_t ws_size,
                              hipStream_t stream) {
    const float* f0 = (const float*)d_in[0];
    const float* f1 = (const float*)d_in[1];
    const float* f2 = (const float*)d_in[2];
    const float* f3 = (const float*)d_in[3];
    const float* boxes = (const float*)d_in[4];
    float* out = (float*)d_out;

    int N = in_sizes[4] / 6;
    int C = out_size / (N * NVOX);

    auto cdim = [&](int sz) {
        int per_c = sz / C;
        return (int)(cbrtf((float)per_c) + 0.5f);
    };
    int d0 = cdim(in_sizes[0]);
    int d1 = cdim(in_sizes[1]);
    int d2 = cdim(in_sizes[2]);
    int d3 = cdim(in_sizes[3]);

    long S0 = (long)d0 * d0 * d0, S1 = (long)d1 * d1 * d1;
    long S2 = (long)d2 * d2 * d2, S3 = (long)d3 * d3 * d3;
    long off0 = 0, off1 = S0 * C, off2 = off1 + S1 * C, off3 = off2 + S2 * C;
    size_t need = (size_t)(off3 + S3 * C) * sizeof(u16);

    bool fast = (C == 64) && (ws_size >= need) &&
                (S0 % 64 == 0) && (S1 % 64 == 0) && (S2 % 64 == 0) && (S3 % 64 == 0);

    if (fast) {
        u16* ws = (u16*)d_ws;
        int t1 = (int)(S0 / 64);
        int t2 = t1 + (int)(S1 / 64);
        int t3 = t2 + (int)(S2 / 64);
        int tt = t3 + (int)(S3 / 64);
        transpose_bf16_kernel<<<tt, 256, 0, stream>>>(f0, f1, f2, f3, ws,
                                                      t1, t2, t3,
                                                      S0, S1, S2, S3,
                                                      off0, off1, off2, off3);
        int nb8 = ((N + 7) / 8) * 8;           // swizzle block count (bijective for N%8==0)
        int nblk = nb8 * NCH2;
        roi_align_cl_kernel<<<nblk, 256, 0, stream>>>(ws, boxes, out, N, C,
                                                      d0, d1, d2, d3,
                                                      off0, off1, off2, off3);
    } else {
        dim3 grid(C, N);
        roi_align_fallback_kernel<<<grid, FBLK, 0, stream>>>(f0, f1, f2, f3, boxes, out,
                                                             N, C, d0, d1, d2, d3);
    }
}